// Round 1
// baseline (264.373 us; speedup 1.0000x reference)
//
#include <hip/hip_runtime.h>
#include <hip/hip_bf16.h>
#include <math.h>

// Problem constants
#define BATCH 8192
#define NB 9
#define NN 256
#define PMAX 8
#define HID 32
#define ZDIM 2304   // NB*NN

typedef short bf16x8 __attribute__((ext_vector_type(8)));   // 8 bf16 in 4 VGPRs
typedef float f32x4 __attribute__((ext_vector_type(4)));    // MFMA accumulator

static __device__ inline unsigned short f2bf(float f) {
    __hip_bfloat16 h = __float2bfloat16(f);
    return *reinterpret_cast<unsigned short*>(&h);
}

static __device__ inline uint4 pack8(float4 a, float4 b) {
    uint4 u;
    u.x = (unsigned)f2bf(a.x) | ((unsigned)f2bf(a.y) << 16);
    u.y = (unsigned)f2bf(a.z) | ((unsigned)f2bf(a.w) << 16);
    u.z = (unsigned)f2bf(b.x) | ((unsigned)f2bf(b.y) << 16);
    u.w = (unsigned)f2bf(b.z) | ((unsigned)f2bf(b.w) << 16);
    return u;
}

// ---------------- K0: pack weights to bf16 ------------------------------------
__global__ __launch_bounds__(256) void k_pack(
    const float* __restrict__ W, const float* __restrict__ gW1,
    unsigned short* __restrict__ Wb, unsigned short* __restrict__ WTb,
    unsigned short* __restrict__ gW1b, unsigned short* __restrict__ g1Tb) {
    int r = blockIdx.z;
    int t = threadIdx.x;
    if (r < 8) {
        __shared__ float tt[32][33];
        int i0 = blockIdx.y * 32;
        int j0 = blockIdx.x * 32;
        int tx = t & 31;
        int ty = t >> 5;
        const float* src = W + (size_t)r * 65536;
        #pragma unroll
        for (int s = 0; s < 32; s += 8) {
            float v = src[(size_t)(i0 + ty + s) * 256 + (j0 + tx)];
            tt[ty + s][tx] = v;
            Wb[(size_t)r * 65536 + (size_t)(i0 + ty + s) * 256 + (j0 + tx)] = f2bf(v);
        }
        __syncthreads();
        #pragma unroll
        for (int s = 0; s < 32; s += 8)
            WTb[(size_t)r * 65536 + (size_t)(j0 + ty + s) * 256 + (i0 + tx)] = f2bf(tt[tx][ty + s]);
    } else {
        int tg = (blockIdx.y * 8 + blockIdx.x) * 256 + t;       // 0..16383
        for (int e = tg; e < 73728; e += 16384) {
            float v = gW1[e];
            unsigned short b = f2bf(v);
            gW1b[e] = b;
            int k = e >> 13, n = (e >> 5) & 255, h = e & 31;
            g1Tb[(size_t)(k * 32 + h) * 256 + n] = b;
        }
    }
}

// -------------------- K1 (MFMA): d1[k][b][h] = silu'(a1) * upstream -----------
__global__ __launch_bounds__(256) void k_mlp(
    const float* __restrict__ z, const unsigned short* __restrict__ g1Tb,
    const float* __restrict__ gb1, const float* __restrict__ gW2,
    const float* __restrict__ gb2, const float* __restrict__ gW3,
    float* __restrict__ d1ws) {
    __shared__ uint4 As4[512];    // 128 rows x 32 k bf16 (reused for h1 / da2)
    __shared__ uint4 Bw[1024];    // gW1^T block: 32 h x 256 n bf16, 8 chunk-regions
    __shared__ uint4 W2Ts4[128];  // W2^T [g][h] bf16 (fragment layout)
    __shared__ uint4 W2Ns4[128];  // W2 natural [h][g] bf16 (fragment layout)

    int t = threadIdx.x;
    int lane = t & 63;
    int w = t >> 6;
    int k = blockIdx.y;
    int b0 = blockIdx.x * 128;

    // ---- stage B (gW1^T) and W2 tiles ----
    const unsigned short* bsrc = g1Tb + (size_t)k * 8192;
    for (int e = t; e < 1024; e += 256) {
        int h = e >> 5;
        int rest = e & 31;
        int c = rest >> 2, q = rest & 3;
        Bw[c * 128 + (h & 15) + 16 * q + 64 * (h >> 4)] =
            *(const uint4*)(bsrc + (size_t)h * 256 + c * 32 + q * 8);
    }
    const float* gw2 = gW2 + (size_t)k * 1024;
    unsigned short* w2t = (unsigned short*)W2Ts4;
    unsigned short* w2n = (unsigned short*)W2Ns4;
    for (int e = t; e < 1024; e += 256) {
        int n = e >> 5, kk = e & 31;
        int q = kk >> 3, jj = kk & 7;
        int ci = (n & 15) + 16 * q + 64 * (n >> 4);
        w2t[ci * 8 + jj] = f2bf(gw2[kk * 32 + n]);   // W2T[g=n][h=kk]
        w2n[ci * 8 + jj] = f2bf(gw2[n * 32 + kk]);   // W2N[h=n][g=kk]
    }

    int mq_m = t >> 2;
    int q = t & 3;

    // ---- layer-1 GEMM: acc1 = z_k @ gW1[k] ----
    f32x4 acc1[2][2];
    #pragma unroll
    for (int i = 0; i < 2; ++i)
        #pragma unroll
        for (int j = 0; j < 2; ++j) acc1[i][j] = (f32x4){0.f, 0.f, 0.f, 0.f};

    for (int c = 0; c < 8; ++c) {
        float4 fa[2][2];
        #pragma unroll
        for (int pp = 0; pp < 2; ++pp) {
            int m = mq_m + 64 * pp;
            const float* as = z + (size_t)(b0 + m) * ZDIM + k * 256 + c * 32 + q * 8;
            fa[pp][0] = *(const float4*)(as);
            fa[pp][1] = *(const float4*)(as + 4);
        }
        __syncthreads();
        #pragma unroll
        for (int pp = 0; pp < 2; ++pp) {
            int m = mq_m + 64 * pp;
            As4[(m & 15) + 16 * q + 64 * (m >> 4)] = pack8(fa[pp][0], fa[pp][1]);
        }
        __syncthreads();
        bf16x8 af[2], bfr[2];
        #pragma unroll
        for (int i = 0; i < 2; ++i) af[i] = __builtin_bit_cast(bf16x8, As4[lane + (w * 2 + i) * 64]);
        #pragma unroll
        for (int j = 0; j < 2; ++j) bfr[j] = __builtin_bit_cast(bf16x8, Bw[c * 128 + lane + j * 64]);
        #pragma unroll
        for (int i = 0; i < 2; ++i)
            #pragma unroll
            for (int j = 0; j < 2; ++j)
                acc1[i][j] = __builtin_amdgcn_mfma_f32_16x16x32_bf16(af[i], bfr[j], acc1[i][j], 0, 0, 0);
    }

    // ---- bias + silu; keep silu'(a1); h1 -> LDS (chunk-swizzled bf16) ----
    int cq = lane >> 4;        // C-layout row quad
    int ci16 = lane & 15;      // C-layout col
    float b1v[2], b2v[2], g3v[2];
    #pragma unroll
    for (int j = 0; j < 2; ++j) {
        b1v[j] = gb1[k * 32 + j * 16 + ci16];
        b2v[j] = gb2[k * 32 + j * 16 + ci16];
        g3v[j] = gW3[k * 32 + j * 16 + ci16];
    }
    unsigned short* Hs = (unsigned short*)As4;
    float sp1[2][2][4];
    __syncthreads();           // all stage-1 As4 reads done
    #pragma unroll
    for (int i = 0; i < 2; ++i)
        #pragma unroll
        for (int j = 0; j < 2; ++j)
            #pragma unroll
            for (int r = 0; r < 4; ++r) {
                float a1 = acc1[i][j][r] + b1v[j];
                float s1 = 1.f / (1.f + __expf(-a1));
                sp1[i][j][r] = s1 * (1.f + a1 * (1.f - s1));
                int row = w * 32 + i * 16 + cq * 4 + r;
                int col = j * 16 + ci16;
                int chunk = (row & 15) + 16 * (col >> 3) + 64 * (row >> 4);
                Hs[chunk * 8 + (col & 7)] = f2bf(a1 * s1);
            }
    __syncthreads();

    // ---- layer-2: a2 = h1 @ W2 ----
    bf16x8 af2[2], wf[2];
    #pragma unroll
    for (int i = 0; i < 2; ++i) af2[i] = __builtin_bit_cast(bf16x8, As4[lane + (w * 2 + i) * 64]);
    #pragma unroll
    for (int j = 0; j < 2; ++j) wf[j] = __builtin_bit_cast(bf16x8, W2Ts4[lane + j * 64]);
    f32x4 acc2[2][2];
    #pragma unroll
    for (int i = 0; i < 2; ++i)
        #pragma unroll
        for (int j = 0; j < 2; ++j) {
            acc2[i][j] = (f32x4){0.f, 0.f, 0.f, 0.f};
            acc2[i][j] = __builtin_amdgcn_mfma_f32_16x16x32_bf16(af2[i], wf[j], acc2[i][j], 0, 0, 0);
        }

    // ---- da2 = gW3 * silu'(a2) -> LDS ----
    __syncthreads();           // h1 reads done
    #pragma unroll
    for (int i = 0; i < 2; ++i)
        #pragma unroll
        for (int j = 0; j < 2; ++j)
            #pragma unroll
            for (int r = 0; r < 4; ++r) {
                float a2 = acc2[i][j][r] + b2v[j];
                float s2 = 1.f / (1.f + __expf(-a2));
                float da2 = g3v[j] * s2 * (1.f + a2 * (1.f - s2));
                int row = w * 32 + i * 16 + cq * 4 + r;
                int col = j * 16 + ci16;
                int chunk = (row & 15) + 16 * (col >> 3) + 64 * (row >> 4);
                Hs[chunk * 8 + (col & 7)] = f2bf(da2);
            }
    __syncthreads();

    // ---- layer-3: dh1 = da2 @ W2^T; d1 = dh1 * silu'(a1) -> global ----
    bf16x8 af3[2], wg[2];
    #pragma unroll
    for (int i = 0; i < 2; ++i) af3[i] = __builtin_bit_cast(bf16x8, As4[lane + (w * 2 + i) * 64]);
    #pragma unroll
    for (int j = 0; j < 2; ++j) wg[j] = __builtin_bit_cast(bf16x8, W2Ns4[lane + j * 64]);
    #pragma unroll
    for (int i = 0; i < 2; ++i)
        #pragma unroll
        for (int j = 0; j < 2; ++j) {
            f32x4 a3 = (f32x4){0.f, 0.f, 0.f, 0.f};
            a3 = __builtin_amdgcn_mfma_f32_16x16x32_bf16(af3[i], wg[j], a3, 0, 0, 0);
            #pragma unroll
            for (int r = 0; r < 4; ++r) {
                int row = w * 32 + i * 16 + cq * 4 + r;
                int col = j * 16 + ci16;
                d1ws[((size_t)k * BATCH + b0 + row) * 32 + col] = a3[r] * sp1[i][j][r];
            }
        }
}

// ---- K2 (MFMA): out[:, 0:2048] = -(z8 @ W[7-k]  +  d1_k @ gW1[k]^T) -----------
// Extended: blockIdx.x in [16,18) handles k==8, i.e. writes the INIT value
// out[:, 2048:] = -(d1_8 @ gW1[8]^T); k_hi then atomically adds the lag terms.
__global__ __launch_bounds__(256) void k_gemm_lo(
    const float* __restrict__ z, const float* __restrict__ d1,
    const unsigned short* __restrict__ WTb, const unsigned short* __restrict__ gW1b,
    float* __restrict__ out) {
    __shared__ uint4 As4[512];   // 128 rows x 32 k (bf16) = 8 KB
    __shared__ uint4 Bs4[512];   // 128 cols x 32 k (bf16) = 8 KB

    int t = threadIdx.x;
    int lane = t & 63;
    int w = t >> 6;
    int wr = w >> 1, wc = w & 1;
    int b0 = blockIdx.y * 128;
    int n0 = blockIdx.x * 128;
    int k  = n0 >> 8;            // block index 0..8 (8 == future-block init)
    int jb = n0 & 255;           // 0 or 128

    const float* Amain = z + (size_t)b0 * ZDIM + 2048;
    const float* Aext  = d1 + ((size_t)k * BATCH + b0) * 32;
    const unsigned short* Bmain = WTb + (size_t)((7 - k) & 7) * 65536 + (size_t)jb * 256;
    const unsigned short* Bext  = gW1b + ((size_t)k * 256 + jb) * 32;

    int mq_m = t >> 2;
    int q    = t & 3;

    f32x4 acc[4][4];
    #pragma unroll
    for (int i = 0; i < 4; ++i)
        #pragma unroll
        for (int j = 0; j < 4; ++j) acc[i][j] = (f32x4){0.f, 0.f, 0.f, 0.f};

    int cstart = (k == 8) ? 8 : 0;
    for (int c = cstart; c < 9; ++c) {
        int kb = c * 32;
        float4 fa[2][2];
        uint4 bu[2];
        #pragma unroll
        for (int pp = 0; pp < 2; ++pp) {
            int m = mq_m + 64 * pp;
            const float* as = (c < 8) ? (Amain + (size_t)m * ZDIM + kb + q * 8)
                                      : (Aext + (size_t)m * 32 + q * 8);
            fa[pp][0] = *(const float4*)(as);
            fa[pp][1] = *(const float4*)(as + 4);
            const unsigned short* bs = (c < 8) ? (Bmain + (size_t)m * 256 + kb + q * 8)
                                               : (Bext + (size_t)m * 32 + q * 8);
            bu[pp] = *(const uint4*)(bs);
        }
        __syncthreads();
        #pragma unroll
        for (int pp = 0; pp < 2; ++pp) {
            int m = mq_m + 64 * pp;
            int ci = (m & 15) + 16 * q + 64 * (m >> 4);
            As4[ci] = pack8(fa[pp][0], fa[pp][1]);
            Bs4[ci] = bu[pp];
        }
        __syncthreads();
        bf16x8 af[4], bf[4];
        #pragma unroll
        for (int i = 0; i < 4; ++i) af[i] = __builtin_bit_cast(bf16x8, As4[lane + (wr * 4 + i) * 64]);
        #pragma unroll
        for (int j = 0; j < 4; ++j) bf[j] = __builtin_bit_cast(bf16x8, Bs4[lane + (wc * 4 + j) * 64]);
        #pragma unroll
        for (int i = 0; i < 4; ++i)
            #pragma unroll
            for (int j = 0; j < 4; ++j)
                acc[i][j] = __builtin_amdgcn_mfma_f32_16x16x32_bf16(af[i], bf[j], acc[i][j], 0, 0, 0);
    }

    int rquad = lane >> 4;
    int cidx  = lane & 15;
    #pragma unroll
    for (int i = 0; i < 4; ++i) {
        #pragma unroll
        for (int j = 0; j < 4; ++j) {
            float* o = out + (size_t)(b0 + wr * 64 + i * 16 + rquad * 4) * ZDIM
                     + (k * 256 + jb + wc * 64 + j * 16 + cidx);
            #pragma unroll
            for (int r = 0; r < 4; ++r)
                o[(size_t)r * ZDIM] = -acc[i][j][r];
        }
    }
}

// ---- K3 (MFMA, split-K over lags): out[:, 2048:] -= z_lg @ W[7-lg]^T ----------
// Grid: (x=64 row-blocks, y=2 col-blocks, z=8 lags) = 1024 WGs (4/CU).
// Each WG: 128x128 tile, K=256 (8 k-steps). Epilogue: native f32 atomic add.
// x fastest-varying => the 2 col-WGs sharing an A panel have IDs differing by
// 64 (== 0 mod 8 XCDs) => same XCD L2 absorbs the 2x A read.
__global__ __launch_bounds__(256) void k_hi(
    const float* __restrict__ z, const unsigned short* __restrict__ Wb,
    float* __restrict__ out) {
    __shared__ uint4 As4[512];   // 128 rows x 32 k (bf16) = 8 KB
    __shared__ uint4 Bs4[512];   // 128 cols x 32 k (bf16) = 8 KB

    int t = threadIdx.x;
    int lane = t & 63;
    int w = t >> 6;
    int wr = w >> 1, wc = w & 1;
    int b0 = blockIdx.x * 128;   // batch rows
    int jb = blockIdx.y * 128;   // hi output col block: 0 or 128
    int lg = blockIdx.z;         // source z-block index m: term z_m @ W[7-m]^T

    const float* Amain = z + (size_t)b0 * ZDIM + lg * 256;
    const unsigned short* Bmain = Wb + (size_t)(7 - lg) * 65536 + (size_t)jb * 256;

    int mq_m = t >> 2;
    int q    = t & 3;

    f32x4 acc[4][4];
    #pragma unroll
    for (int i = 0; i < 4; ++i)
        #pragma unroll
        for (int j = 0; j < 4; ++j) acc[i][j] = (f32x4){0.f, 0.f, 0.f, 0.f};

    for (int c = 0; c < 8; ++c) {
        int kb = c * 32;
        float4 fa[2][2];
        uint4 bu[2];
        #pragma unroll
        for (int pp = 0; pp < 2; ++pp) {
            int m = mq_m + 64 * pp;
            const float* as = Amain + (size_t)m * ZDIM + kb + q * 8;
            fa[pp][0] = *(const float4*)(as);
            fa[pp][1] = *(const float4*)(as + 4);
            bu[pp] = *(const uint4*)(Bmain + (size_t)m * 256 + kb + q * 8);
        }
        __syncthreads();
        #pragma unroll
        for (int pp = 0; pp < 2; ++pp) {
            int m = mq_m + 64 * pp;
            int ci = (m & 15) + 16 * q + 64 * (m >> 4);
            As4[ci] = pack8(fa[pp][0], fa[pp][1]);
            Bs4[ci] = bu[pp];
        }
        __syncthreads();
        bf16x8 af[4], bf[4];
        #pragma unroll
        for (int i = 0; i < 4; ++i) af[i] = __builtin_bit_cast(bf16x8, As4[lane + (wr * 4 + i) * 64]);
        #pragma unroll
        for (int j = 0; j < 4; ++j) bf[j] = __builtin_bit_cast(bf16x8, Bs4[lane + (wc * 4 + j) * 64]);
        #pragma unroll
        for (int i = 0; i < 4; ++i)
            #pragma unroll
            for (int j = 0; j < 4; ++j)
                acc[i][j] = __builtin_amdgcn_mfma_f32_16x16x32_bf16(af[i], bf[j], acc[i][j], 0, 0, 0);
    }

    int rquad = lane >> 4;
    int cidx  = lane & 15;
    #pragma unroll
    for (int i = 0; i < 4; ++i) {
        #pragma unroll
        for (int j = 0; j < 4; ++j) {
            float* o = out + (size_t)(b0 + wr * 64 + i * 16 + rquad * 4) * ZDIM
                     + (2048 + jb + wc * 64 + j * 16 + cidx);
            #pragma unroll
            for (int r = 0; r < 4; ++r)
                unsafeAtomicAdd(o + (size_t)r * ZDIM, -acc[i][j][r]);
        }
    }
}

extern "C" void kernel_launch(void* const* d_in, const int* in_sizes, int n_in,
                              void* d_out, int out_size, void* d_ws, size_t ws_size,
                              hipStream_t stream) {
    const float* z   = (const float*)d_in[0];
    const float* gW1 = (const float*)d_in[1];
    const float* gb1 = (const float*)d_in[2];
    const float* gW2 = (const float*)d_in[3];
    const float* gb2 = (const float*)d_in[4];
    const float* gW3 = (const float*)d_in[5];
    // d_in[6] = gb3: constant, no grad
    const float* W   = (const float*)d_in[7];
    float* out = (float*)d_out;

    float* ws = (float*)d_ws;
    float*          d1ws = ws;                               // 2359296 f32 (9.4 MB)
    unsigned short* Wb   = (unsigned short*)(ws + 2359296);  // 524288 bf16
    unsigned short* WTb  = Wb + 524288;                      // 524288 bf16
    unsigned short* gW1b = WTb + 524288;                     // 73728 bf16
    unsigned short* g1Tb = gW1b + 73728;                     // 73728 bf16 (~11.8 MB total)

    k_pack<<<dim3(8, 8, 9), 256, 0, stream>>>(W, gW1, Wb, WTb, gW1b, g1Tb);
    k_mlp<<<dim3(64, 9), 256, 0, stream>>>(z, g1Tb, gb1, gW2, gb2, gW3, d1ws);
    k_gemm_lo<<<dim3(18, 64), 256, 0, stream>>>(z, d1ws, WTb, gW1b, out);
    k_hi<<<dim3(64, 2, 8), 256, 0, stream>>>(z, Wb, out);
}

// Round 2
// 222.472 us; speedup vs baseline: 1.1883x; 1.1883x over previous
//
#include <hip/hip_runtime.h>
#include <hip/hip_bf16.h>
#include <math.h>

// Problem constants
#define BATCH 8192
#define NB 9
#define NN 256
#define PMAX 8
#define HID 32
#define ZDIM 2304   // NB*NN

typedef short bf16x8 __attribute__((ext_vector_type(8)));   // 8 bf16 in 4 VGPRs
typedef float f32x4 __attribute__((ext_vector_type(4)));    // MFMA accumulator

static __device__ inline unsigned short f2bf(float f) {
    __hip_bfloat16 h = __float2bfloat16(f);
    return *reinterpret_cast<unsigned short*>(&h);
}

static __device__ inline uint4 pack8(float4 a, float4 b) {
    uint4 u;
    u.x = (unsigned)f2bf(a.x) | ((unsigned)f2bf(a.y) << 16);
    u.y = (unsigned)f2bf(a.z) | ((unsigned)f2bf(a.w) << 16);
    u.z = (unsigned)f2bf(b.x) | ((unsigned)f2bf(b.y) << 16);
    u.w = (unsigned)f2bf(b.z) | ((unsigned)f2bf(b.w) << 16);
    return u;
}

// ---------------- K0: pack weights to bf16 ------------------------------------
__global__ __launch_bounds__(256) void k_pack(
    const float* __restrict__ W, const float* __restrict__ gW1,
    unsigned short* __restrict__ Wb, unsigned short* __restrict__ WTb,
    unsigned short* __restrict__ gW1b, unsigned short* __restrict__ g1Tb) {
    int r = blockIdx.z;
    int t = threadIdx.x;
    if (r < 8) {
        __shared__ float tt[32][33];
        int i0 = blockIdx.y * 32;
        int j0 = blockIdx.x * 32;
        int tx = t & 31;
        int ty = t >> 5;
        const float* src = W + (size_t)r * 65536;
        #pragma unroll
        for (int s = 0; s < 32; s += 8) {
            float v = src[(size_t)(i0 + ty + s) * 256 + (j0 + tx)];
            tt[ty + s][tx] = v;
            Wb[(size_t)r * 65536 + (size_t)(i0 + ty + s) * 256 + (j0 + tx)] = f2bf(v);
        }
        __syncthreads();
        #pragma unroll
        for (int s = 0; s < 32; s += 8)
            WTb[(size_t)r * 65536 + (size_t)(j0 + ty + s) * 256 + (i0 + tx)] = f2bf(tt[tx][ty + s]);
    } else {
        int tg = (blockIdx.y * 8 + blockIdx.x) * 256 + t;       // 0..16383
        for (int e = tg; e < 73728; e += 16384) {
            float v = gW1[e];
            unsigned short b = f2bf(v);
            gW1b[e] = b;
            int k = e >> 13, n = (e >> 5) & 255, h = e & 31;
            g1Tb[(size_t)(k * 32 + h) * 256 + n] = b;
        }
    }
}

// -------------------- K1 (MFMA): d1[k][b][h] = silu'(a1) * upstream -----------
__global__ __launch_bounds__(256) void k_mlp(
    const float* __restrict__ z, const unsigned short* __restrict__ g1Tb,
    const float* __restrict__ gb1, const float* __restrict__ gW2,
    const float* __restrict__ gb2, const float* __restrict__ gW3,
    float* __restrict__ d1ws) {
    __shared__ uint4 As4[512];    // 128 rows x 32 k bf16 (reused for h1 / da2)
    __shared__ uint4 Bw[1024];    // gW1^T block: 32 h x 256 n bf16, 8 chunk-regions
    __shared__ uint4 W2Ts4[128];  // W2^T [g][h] bf16 (fragment layout)
    __shared__ uint4 W2Ns4[128];  // W2 natural [h][g] bf16 (fragment layout)

    int t = threadIdx.x;
    int lane = t & 63;
    int w = t >> 6;
    int k = blockIdx.y;
    int b0 = blockIdx.x * 128;

    // ---- stage B (gW1^T) and W2 tiles ----
    const unsigned short* bsrc = g1Tb + (size_t)k * 8192;
    for (int e = t; e < 1024; e += 256) {
        int h = e >> 5;
        int rest = e & 31;
        int c = rest >> 2, q = rest & 3;
        Bw[c * 128 + (h & 15) + 16 * q + 64 * (h >> 4)] =
            *(const uint4*)(bsrc + (size_t)h * 256 + c * 32 + q * 8);
    }
    const float* gw2 = gW2 + (size_t)k * 1024;
    unsigned short* w2t = (unsigned short*)W2Ts4;
    unsigned short* w2n = (unsigned short*)W2Ns4;
    for (int e = t; e < 1024; e += 256) {
        int n = e >> 5, kk = e & 31;
        int q = kk >> 3, jj = kk & 7;
        int ci = (n & 15) + 16 * q + 64 * (n >> 4);
        w2t[ci * 8 + jj] = f2bf(gw2[kk * 32 + n]);   // W2T[g=n][h=kk]
        w2n[ci * 8 + jj] = f2bf(gw2[n * 32 + kk]);   // W2N[h=n][g=kk]
    }

    int mq_m = t >> 2;
    int q = t & 3;

    // ---- layer-1 GEMM: acc1 = z_k @ gW1[k] ----
    f32x4 acc1[2][2];
    #pragma unroll
    for (int i = 0; i < 2; ++i)
        #pragma unroll
        for (int j = 0; j < 2; ++j) acc1[i][j] = (f32x4){0.f, 0.f, 0.f, 0.f};

    for (int c = 0; c < 8; ++c) {
        float4 fa[2][2];
        #pragma unroll
        for (int pp = 0; pp < 2; ++pp) {
            int m = mq_m + 64 * pp;
            const float* as = z + (size_t)(b0 + m) * ZDIM + k * 256 + c * 32 + q * 8;
            fa[pp][0] = *(const float4*)(as);
            fa[pp][1] = *(const float4*)(as + 4);
        }
        __syncthreads();
        #pragma unroll
        for (int pp = 0; pp < 2; ++pp) {
            int m = mq_m + 64 * pp;
            As4[(m & 15) + 16 * q + 64 * (m >> 4)] = pack8(fa[pp][0], fa[pp][1]);
        }
        __syncthreads();
        bf16x8 af[2], bfr[2];
        #pragma unroll
        for (int i = 0; i < 2; ++i) af[i] = __builtin_bit_cast(bf16x8, As4[lane + (w * 2 + i) * 64]);
        #pragma unroll
        for (int j = 0; j < 2; ++j) bfr[j] = __builtin_bit_cast(bf16x8, Bw[c * 128 + lane + j * 64]);
        #pragma unroll
        for (int i = 0; i < 2; ++i)
            #pragma unroll
            for (int j = 0; j < 2; ++j)
                acc1[i][j] = __builtin_amdgcn_mfma_f32_16x16x32_bf16(af[i], bfr[j], acc1[i][j], 0, 0, 0);
    }

    // ---- bias + silu; keep silu'(a1); h1 -> LDS (chunk-swizzled bf16) ----
    int cq = lane >> 4;        // C-layout row quad
    int ci16 = lane & 15;      // C-layout col
    float b1v[2], b2v[2], g3v[2];
    #pragma unroll
    for (int j = 0; j < 2; ++j) {
        b1v[j] = gb1[k * 32 + j * 16 + ci16];
        b2v[j] = gb2[k * 32 + j * 16 + ci16];
        g3v[j] = gW3[k * 32 + j * 16 + ci16];
    }
    unsigned short* Hs = (unsigned short*)As4;
    float sp1[2][2][4];
    __syncthreads();           // all stage-1 As4 reads done
    #pragma unroll
    for (int i = 0; i < 2; ++i)
        #pragma unroll
        for (int j = 0; j < 2; ++j)
            #pragma unroll
            for (int r = 0; r < 4; ++r) {
                float a1 = acc1[i][j][r] + b1v[j];
                float s1 = 1.f / (1.f + __expf(-a1));
                sp1[i][j][r] = s1 * (1.f + a1 * (1.f - s1));
                int row = w * 32 + i * 16 + cq * 4 + r;
                int col = j * 16 + ci16;
                int chunk = (row & 15) + 16 * (col >> 3) + 64 * (row >> 4);
                Hs[chunk * 8 + (col & 7)] = f2bf(a1 * s1);
            }
    __syncthreads();

    // ---- layer-2: a2 = h1 @ W2 ----
    bf16x8 af2[2], wf[2];
    #pragma unroll
    for (int i = 0; i < 2; ++i) af2[i] = __builtin_bit_cast(bf16x8, As4[lane + (w * 2 + i) * 64]);
    #pragma unroll
    for (int j = 0; j < 2; ++j) wf[j] = __builtin_bit_cast(bf16x8, W2Ts4[lane + j * 64]);
    f32x4 acc2[2][2];
    #pragma unroll
    for (int i = 0; i < 2; ++i)
        #pragma unroll
        for (int j = 0; j < 2; ++j) {
            acc2[i][j] = (f32x4){0.f, 0.f, 0.f, 0.f};
            acc2[i][j] = __builtin_amdgcn_mfma_f32_16x16x32_bf16(af2[i], wf[j], acc2[i][j], 0, 0, 0);
        }

    // ---- da2 = gW3 * silu'(a2) -> LDS ----
    __syncthreads();           // h1 reads done
    #pragma unroll
    for (int i = 0; i < 2; ++i)
        #pragma unroll
        for (int j = 0; j < 2; ++j)
            #pragma unroll
            for (int r = 0; r < 4; ++r) {
                float a2 = acc2[i][j][r] + b2v[j];
                float s2 = 1.f / (1.f + __expf(-a2));
                float da2 = g3v[j] * s2 * (1.f + a2 * (1.f - s2));
                int row = w * 32 + i * 16 + cq * 4 + r;
                int col = j * 16 + ci16;
                int chunk = (row & 15) + 16 * (col >> 3) + 64 * (row >> 4);
                Hs[chunk * 8 + (col & 7)] = f2bf(da2);
            }
    __syncthreads();

    // ---- layer-3: dh1 = da2 @ W2^T; d1 = dh1 * silu'(a1) -> global ----
    bf16x8 af3[2], wg[2];
    #pragma unroll
    for (int i = 0; i < 2; ++i) af3[i] = __builtin_bit_cast(bf16x8, As4[lane + (w * 2 + i) * 64]);
    #pragma unroll
    for (int j = 0; j < 2; ++j) wg[j] = __builtin_bit_cast(bf16x8, W2Ns4[lane + j * 64]);
    #pragma unroll
    for (int i = 0; i < 2; ++i)
        #pragma unroll
        for (int j = 0; j < 2; ++j) {
            f32x4 a3 = (f32x4){0.f, 0.f, 0.f, 0.f};
            a3 = __builtin_amdgcn_mfma_f32_16x16x32_bf16(af3[i], wg[j], a3, 0, 0, 0);
            #pragma unroll
            for (int r = 0; r < 4; ++r) {
                int row = w * 32 + i * 16 + cq * 4 + r;
                int col = j * 16 + ci16;
                d1ws[((size_t)k * BATCH + b0 + row) * 32 + col] = a3[r] * sp1[i][j][r];
            }
        }
}

// ---- K2 (MFMA): out[:, 0:2048] = -(z8 @ W[7-k]  +  d1_k @ gW1[k]^T) -----------
// Grid (x=64 row-blocks, y=16 col-blocks): the 16 col-WGs sharing an A panel
// (z[:, 2048:] rows b0..b0+127) have linear IDs differing by 64 == 0 mod 8
// XCDs -> same XCD L2 absorbs the 16x A re-read.
__global__ __launch_bounds__(256) void k_gemm_lo(
    const float* __restrict__ z, const float* __restrict__ d1,
    const unsigned short* __restrict__ WTb, const unsigned short* __restrict__ gW1b,
    float* __restrict__ out) {
    __shared__ uint4 As4[512];   // 128 rows x 32 k (bf16) = 8 KB
    __shared__ uint4 Bs4[512];   // 128 cols x 32 k (bf16) = 8 KB

    int t = threadIdx.x;
    int lane = t & 63;
    int w = t >> 6;
    int wr = w >> 1, wc = w & 1;
    int b0 = blockIdx.x * 128;
    int n0 = blockIdx.y * 128;
    int k  = n0 >> 8;            // block index 0..7
    int jb = n0 & 255;           // 0 or 128

    const float* Amain = z + (size_t)b0 * ZDIM + 2048;
    const float* Aext  = d1 + ((size_t)k * BATCH + b0) * 32;
    const unsigned short* Bmain = WTb + (size_t)(7 - k) * 65536 + (size_t)jb * 256;
    const unsigned short* Bext  = gW1b + ((size_t)k * 256 + jb) * 32;

    int mq_m = t >> 2;
    int q    = t & 3;

    f32x4 acc[4][4];
    #pragma unroll
    for (int i = 0; i < 4; ++i)
        #pragma unroll
        for (int j = 0; j < 4; ++j) acc[i][j] = (f32x4){0.f, 0.f, 0.f, 0.f};

    for (int c = 0; c < 9; ++c) {
        int kb = c * 32;
        float4 fa[2][2];
        uint4 bu[2];
        #pragma unroll
        for (int pp = 0; pp < 2; ++pp) {
            int m = mq_m + 64 * pp;
            const float* as = (c < 8) ? (Amain + (size_t)m * ZDIM + kb + q * 8)
                                      : (Aext + (size_t)m * 32 + q * 8);
            fa[pp][0] = *(const float4*)(as);
            fa[pp][1] = *(const float4*)(as + 4);
            const unsigned short* bs = (c < 8) ? (Bmain + (size_t)m * 256 + kb + q * 8)
                                               : (Bext + (size_t)m * 32 + q * 8);
            bu[pp] = *(const uint4*)(bs);
        }
        __syncthreads();
        #pragma unroll
        for (int pp = 0; pp < 2; ++pp) {
            int m = mq_m + 64 * pp;
            int ci = (m & 15) + 16 * q + 64 * (m >> 4);
            As4[ci] = pack8(fa[pp][0], fa[pp][1]);
            Bs4[ci] = bu[pp];
        }
        __syncthreads();
        bf16x8 af[4], bf[4];
        #pragma unroll
        for (int i = 0; i < 4; ++i) af[i] = __builtin_bit_cast(bf16x8, As4[lane + (wr * 4 + i) * 64]);
        #pragma unroll
        for (int j = 0; j < 4; ++j) bf[j] = __builtin_bit_cast(bf16x8, Bs4[lane + (wc * 4 + j) * 64]);
        #pragma unroll
        for (int i = 0; i < 4; ++i)
            #pragma unroll
            for (int j = 0; j < 4; ++j)
                acc[i][j] = __builtin_amdgcn_mfma_f32_16x16x32_bf16(af[i], bf[j], acc[i][j], 0, 0, 0);
    }

    int rquad = lane >> 4;
    int cidx  = lane & 15;
    #pragma unroll
    for (int i = 0; i < 4; ++i) {
        #pragma unroll
        for (int j = 0; j < 4; ++j) {
            float* o = out + (size_t)(b0 + wr * 64 + i * 16 + rquad * 4) * ZDIM
                     + (k * 256 + jb + wc * 64 + j * 16 + cidx);
            #pragma unroll
            for (int r = 0; r < 4; ++r)
                o[(size_t)r * ZDIM] = -acc[i][j][r];
        }
    }
}

// ---- K3 (MFMA): out[:, 2048:] = -(sum_m z_m @ W[7-m]^T + d1_8 @ gW1[8]^T) -----
// 64x64 tiles -> grid (x=128 row-blocks, y=4 col-blocks) = 512 WGs = 2 WG/CU,
// so one WG's barrier/vmcnt drain overlaps the other's MFMA + loads.
// Same-A col-WGs differ by 128 in linear ID == 0 mod 8 XCDs -> L2-shared A.
__global__ __launch_bounds__(256) void k_gemm_hi(
    const float* __restrict__ z, const float* __restrict__ d1,
    const unsigned short* __restrict__ Wb, const unsigned short* __restrict__ gW1b,
    float* __restrict__ out) {
    __shared__ uint4 As4[256];   // 64 rows x 32 k (bf16) = 4 KB
    __shared__ uint4 Bs4[256];   // 64 cols x 32 k (bf16) = 4 KB

    int t = threadIdx.x;
    int lane = t & 63;
    int w = t >> 6;
    int wr = w & 1, wc = w >> 1;
    int b0 = blockIdx.x * 64;    // batch rows
    int i0 = blockIdx.y * 64;    // hi output col block

    const float* Amain = z + (size_t)b0 * ZDIM;
    const float* Aext  = d1 + ((size_t)8 * BATCH + b0) * 32;
    const unsigned short* Bext = gW1b + (size_t)(8 * 256 + i0) * 32;

    int m = t >> 2;              // 0..63: A row / B col handled by this thread
    int q = t & 3;               // k-subchunk

    f32x4 acc[2][2];
    #pragma unroll
    for (int i = 0; i < 2; ++i)
        #pragma unroll
        for (int j = 0; j < 2; ++j) acc[i][j] = (f32x4){0.f, 0.f, 0.f, 0.f};

    for (int c = 0; c < 65; ++c) {
        int kb = c * 32;
        const float* as = (c < 64) ? (Amain + (size_t)m * ZDIM + kb + q * 8)
                                   : (Aext + (size_t)m * 32 + q * 8);
        float4 fa0 = *(const float4*)(as);
        float4 fa1 = *(const float4*)(as + 4);
        uint4 bu;
        if (c < 64) {
            int lag = c >> 3;
            int j0  = kb & 255;
            bu = *(const uint4*)(Wb + (size_t)(7 - lag) * 65536 + (size_t)(i0 + m) * 256 + j0 + q * 8);
        } else {
            bu = *(const uint4*)(Bext + (size_t)m * 32 + q * 8);
        }
        __syncthreads();
        int ci = (m & 15) + 16 * q + 64 * (m >> 4);
        As4[ci] = pack8(fa0, fa1);
        Bs4[ci] = bu;
        __syncthreads();
        bf16x8 af[2], bf[2];
        #pragma unroll
        for (int i = 0; i < 2; ++i) af[i] = __builtin_bit_cast(bf16x8, As4[lane + (wr * 2 + i) * 64]);
        #pragma unroll
        for (int j = 0; j < 2; ++j) bf[j] = __builtin_bit_cast(bf16x8, Bs4[lane + (wc * 2 + j) * 64]);
        #pragma unroll
        for (int i = 0; i < 2; ++i)
            #pragma unroll
            for (int j = 0; j < 2; ++j)
                acc[i][j] = __builtin_amdgcn_mfma_f32_16x16x32_bf16(af[i], bf[j], acc[i][j], 0, 0, 0);
    }

    int rquad = lane >> 4;
    int cidx  = lane & 15;
    #pragma unroll
    for (int i = 0; i < 2; ++i) {
        #pragma unroll
        for (int j = 0; j < 2; ++j) {
            float* o = out + (size_t)(b0 + wr * 32 + i * 16 + rquad * 4) * ZDIM
                     + (2048 + i0 + wc * 32 + j * 16 + cidx);
            #pragma unroll
            for (int r = 0; r < 4; ++r)
                o[(size_t)r * ZDIM] = -acc[i][j][r];
        }
    }
}

extern "C" void kernel_launch(void* const* d_in, const int* in_sizes, int n_in,
                              void* d_out, int out_size, void* d_ws, size_t ws_size,
                              hipStream_t stream) {
    const float* z   = (const float*)d_in[0];
    const float* gW1 = (const float*)d_in[1];
    const float* gb1 = (const float*)d_in[2];
    const float* gW2 = (const float*)d_in[3];
    const float* gb2 = (const float*)d_in[4];
    const float* gW3 = (const float*)d_in[5];
    // d_in[6] = gb3: constant, no grad
    const float* W   = (const float*)d_in[7];
    float* out = (float*)d_out;

    float* ws = (float*)d_ws;
    float*          d1ws = ws;                               // 2359296 f32 (9.4 MB)
    unsigned short* Wb   = (unsigned short*)(ws + 2359296);  // 524288 bf16
    unsigned short* WTb  = Wb + 524288;                      // 524288 bf16
    unsigned short* gW1b = WTb + 524288;                     // 73728 bf16
    unsigned short* g1Tb = gW1b + 73728;                     // 73728 bf16 (~11.8 MB total)

    k_pack<<<dim3(8, 8, 9), 256, 0, stream>>>(W, gW1, Wb, WTb, gW1b, g1Tb);
    k_mlp<<<dim3(64, 9), 256, 0, stream>>>(z, g1Tb, gb1, gW2, gb2, gW3, d1ws);
    k_gemm_lo<<<dim3(64, 16), 256, 0, stream>>>(z, d1ws, WTb, gW1b, out);
    k_gemm_hi<<<dim3(128, 4), 256, 0, stream>>>(z, d1ws, Wb, gW1b, out);
}

// Round 3
// 199.847 us; speedup vs baseline: 1.3229x; 1.1132x over previous
//
#include <hip/hip_runtime.h>
#include <hip/hip_bf16.h>
#include <math.h>

// Problem constants
#define BATCH 8192
#define NB 9
#define NN 256
#define PMAX 8
#define HID 32
#define ZDIM 2304   // NB*NN

typedef short bf16x8 __attribute__((ext_vector_type(8)));   // 8 bf16 in 4 VGPRs
typedef float f32x4 __attribute__((ext_vector_type(4)));    // MFMA accumulator

static __device__ inline unsigned short f2bf(float f) {
    __hip_bfloat16 h = __float2bfloat16(f);
    return *reinterpret_cast<unsigned short*>(&h);
}

static __device__ inline uint4 pack8(float4 a, float4 b) {
    uint4 u;
    u.x = (unsigned)f2bf(a.x) | ((unsigned)f2bf(a.y) << 16);
    u.y = (unsigned)f2bf(a.z) | ((unsigned)f2bf(a.w) << 16);
    u.z = (unsigned)f2bf(b.x) | ((unsigned)f2bf(b.y) << 16);
    u.w = (unsigned)f2bf(b.z) | ((unsigned)f2bf(b.w) << 16);
    return u;
}

// ---------------- K0: pack weights to bf16 ------------------------------------
__global__ __launch_bounds__(256) void k_pack(
    const float* __restrict__ W, const float* __restrict__ gW1,
    unsigned short* __restrict__ Wb, unsigned short* __restrict__ WTb,
    unsigned short* __restrict__ gW1b, unsigned short* __restrict__ g1Tb) {
    int r = blockIdx.z;
    int t = threadIdx.x;
    if (r < 8) {
        __shared__ float tt[32][33];
        int i0 = blockIdx.y * 32;
        int j0 = blockIdx.x * 32;
        int tx = t & 31;
        int ty = t >> 5;
        const float* src = W + (size_t)r * 65536;
        #pragma unroll
        for (int s = 0; s < 32; s += 8) {
            float v = src[(size_t)(i0 + ty + s) * 256 + (j0 + tx)];
            tt[ty + s][tx] = v;
            Wb[(size_t)r * 65536 + (size_t)(i0 + ty + s) * 256 + (j0 + tx)] = f2bf(v);
        }
        __syncthreads();
        #pragma unroll
        for (int s = 0; s < 32; s += 8)
            WTb[(size_t)r * 65536 + (size_t)(j0 + ty + s) * 256 + (i0 + tx)] = f2bf(tt[tx][ty + s]);
    } else {
        int tg = (blockIdx.y * 8 + blockIdx.x) * 256 + t;       // 0..16383
        for (int e = tg; e < 73728; e += 16384) {
            float v = gW1[e];
            unsigned short b = f2bf(v);
            gW1b[e] = b;
            int k = e >> 13, n = (e >> 5) & 255, h = e & 31;
            g1Tb[(size_t)(k * 32 + h) * 256 + n] = b;
        }
    }
}

// -------------------- K1 (MFMA): d1[k][b][h] = silu'(a1) * upstream -----------
// L1 K-loop is double-buffered: 1 barrier/step, next z-slice loads issue
// before the MFMAs so HBM latency hides under compute.
__global__ __launch_bounds__(256) void k_mlp(
    const float* __restrict__ z, const unsigned short* __restrict__ g1Tb,
    const float* __restrict__ gb1, const float* __restrict__ gW2,
    const float* __restrict__ gb2, const float* __restrict__ gW3,
    float* __restrict__ d1ws) {
    __shared__ uint4 As4[2][512]; // 2 x (128 rows x 32 k bf16); buf0 reused for h1/da2
    __shared__ uint4 Bw[1024];    // gW1^T block: 32 h x 256 n bf16, 8 chunk-regions
    __shared__ uint4 W2Ts4[128];  // W2^T [g][h] bf16 (fragment layout)
    __shared__ uint4 W2Ns4[128];  // W2 natural [h][g] bf16 (fragment layout)

    int t = threadIdx.x;
    int lane = t & 63;
    int w = t >> 6;
    int k = blockIdx.y;
    int b0 = blockIdx.x * 128;

    // ---- stage B (gW1^T) and W2 tiles ----
    const unsigned short* bsrc = g1Tb + (size_t)k * 8192;
    for (int e = t; e < 1024; e += 256) {
        int h = e >> 5;
        int rest = e & 31;
        int c = rest >> 2, qq = rest & 3;
        Bw[c * 128 + (h & 15) + 16 * qq + 64 * (h >> 4)] =
            *(const uint4*)(bsrc + (size_t)h * 256 + c * 32 + qq * 8);
    }
    const float* gw2 = gW2 + (size_t)k * 1024;
    unsigned short* w2t = (unsigned short*)W2Ts4;
    unsigned short* w2n = (unsigned short*)W2Ns4;
    for (int e = t; e < 1024; e += 256) {
        int n = e >> 5, kk = e & 31;
        int qq = kk >> 3, jj = kk & 7;
        int ci = (n & 15) + 16 * qq + 64 * (n >> 4);
        w2t[ci * 8 + jj] = f2bf(gw2[kk * 32 + n]);   // W2T[g=n][h=kk]
        w2n[ci * 8 + jj] = f2bf(gw2[n * 32 + kk]);   // W2N[h=n][g=kk]
    }

    int mq = t >> 2;
    int q = t & 3;
    int ci0 = (mq & 15) + 16 * q + 64 * (mq >> 4);   // pp=0; pp=1 -> +256

    // ---- layer-1 GEMM: acc1 = z_k @ gW1[k] (pipelined) ----
    f32x4 acc1[2][2];
    #pragma unroll
    for (int i = 0; i < 2; ++i)
        #pragma unroll
        for (int j = 0; j < 2; ++j) acc1[i][j] = (f32x4){0.f, 0.f, 0.f, 0.f};

    auto loadZ = [&](int c, float4 (&fa)[2][2]) {
        #pragma unroll
        for (int pp = 0; pp < 2; ++pp) {
            int m = mq + 64 * pp;
            const float* as = z + (size_t)(b0 + m) * ZDIM + k * 256 + c * 32 + q * 8;
            fa[pp][0] = *(const float4*)(as);
            fa[pp][1] = *(const float4*)(as + 4);
        }
    };
    auto storeA = [&](int buf, float4 (&fa)[2][2]) {
        #pragma unroll
        for (int pp = 0; pp < 2; ++pp)
            As4[buf][ci0 + 256 * pp] = pack8(fa[pp][0], fa[pp][1]);
    };

    {
        float4 fa[2][2];
        loadZ(0, fa);
        storeA(0, fa);
    }
    int cur = 0;
    for (int c = 0; c < 8; ++c) {
        __syncthreads();
        float4 fan[2][2];
        if (c < 7) loadZ(c + 1, fan);
        bf16x8 af[2], bfr[2];
        #pragma unroll
        for (int i = 0; i < 2; ++i) af[i] = __builtin_bit_cast(bf16x8, As4[cur][lane + (w * 2 + i) * 64]);
        #pragma unroll
        for (int j = 0; j < 2; ++j) bfr[j] = __builtin_bit_cast(bf16x8, Bw[c * 128 + lane + j * 64]);
        #pragma unroll
        for (int i = 0; i < 2; ++i)
            #pragma unroll
            for (int j = 0; j < 2; ++j)
                acc1[i][j] = __builtin_amdgcn_mfma_f32_16x16x32_bf16(af[i], bfr[j], acc1[i][j], 0, 0, 0);
        if (c < 7) storeA(cur ^ 1, fan);
        cur ^= 1;
    }

    // ---- bias + silu; keep silu'(a1); h1 -> LDS buf0 (chunk-swizzled bf16) ----
    int cq = lane >> 4;        // C-layout row quad
    int ci16 = lane & 15;      // C-layout col
    float b1v[2], b2v[2], g3v[2];
    #pragma unroll
    for (int j = 0; j < 2; ++j) {
        b1v[j] = gb1[k * 32 + j * 16 + ci16];
        b2v[j] = gb2[k * 32 + j * 16 + ci16];
        g3v[j] = gW3[k * 32 + j * 16 + ci16];
    }
    unsigned short* Hs = (unsigned short*)As4;
    float sp1[2][2][4];
    __syncthreads();           // all stage-1 As4 reads done
    #pragma unroll
    for (int i = 0; i < 2; ++i)
        #pragma unroll
        for (int j = 0; j < 2; ++j)
            #pragma unroll
            for (int r = 0; r < 4; ++r) {
                float a1 = acc1[i][j][r] + b1v[j];
                float s1 = 1.f / (1.f + __expf(-a1));
                sp1[i][j][r] = s1 * (1.f + a1 * (1.f - s1));
                int row = w * 32 + i * 16 + cq * 4 + r;
                int col = j * 16 + ci16;
                int chunk = (row & 15) + 16 * (col >> 3) + 64 * (row >> 4);
                Hs[chunk * 8 + (col & 7)] = f2bf(a1 * s1);
            }
    __syncthreads();

    // ---- layer-2: a2 = h1 @ W2 ----
    bf16x8 af2[2], wf[2];
    #pragma unroll
    for (int i = 0; i < 2; ++i) af2[i] = __builtin_bit_cast(bf16x8, As4[0][lane + (w * 2 + i) * 64]);
    #pragma unroll
    for (int j = 0; j < 2; ++j) wf[j] = __builtin_bit_cast(bf16x8, W2Ts4[lane + j * 64]);
    f32x4 acc2[2][2];
    #pragma unroll
    for (int i = 0; i < 2; ++i)
        #pragma unroll
        for (int j = 0; j < 2; ++j) {
            acc2[i][j] = (f32x4){0.f, 0.f, 0.f, 0.f};
            acc2[i][j] = __builtin_amdgcn_mfma_f32_16x16x32_bf16(af2[i], wf[j], acc2[i][j], 0, 0, 0);
        }

    // ---- da2 = gW3 * silu'(a2) -> LDS buf0 ----
    __syncthreads();           // h1 reads done
    #pragma unroll
    for (int i = 0; i < 2; ++i)
        #pragma unroll
        for (int j = 0; j < 2; ++j)
            #pragma unroll
            for (int r = 0; r < 4; ++r) {
                float a2 = acc2[i][j][r] + b2v[j];
                float s2 = 1.f / (1.f + __expf(-a2));
                float da2 = g3v[j] * s2 * (1.f + a2 * (1.f - s2));
                int row = w * 32 + i * 16 + cq * 4 + r;
                int col = j * 16 + ci16;
                int chunk = (row & 15) + 16 * (col >> 3) + 64 * (row >> 4);
                Hs[chunk * 8 + (col & 7)] = f2bf(da2);
            }
    __syncthreads();

    // ---- layer-3: dh1 = da2 @ W2^T; d1 = dh1 * silu'(a1) -> global ----
    bf16x8 af3[2], wg[2];
    #pragma unroll
    for (int i = 0; i < 2; ++i) af3[i] = __builtin_bit_cast(bf16x8, As4[0][lane + (w * 2 + i) * 64]);
    #pragma unroll
    for (int j = 0; j < 2; ++j) wg[j] = __builtin_bit_cast(bf16x8, W2Ns4[lane + j * 64]);
    #pragma unroll
    for (int i = 0; i < 2; ++i)
        #pragma unroll
        for (int j = 0; j < 2; ++j) {
            f32x4 a3 = (f32x4){0.f, 0.f, 0.f, 0.f};
            a3 = __builtin_amdgcn_mfma_f32_16x16x32_bf16(af3[i], wg[j], a3, 0, 0, 0);
            #pragma unroll
            for (int r = 0; r < 4; ++r) {
                int row = w * 32 + i * 16 + cq * 4 + r;
                int col = j * 16 + ci16;
                d1ws[((size_t)k * BATCH + b0 + row) * 32 + col] = a3[r] * sp1[i][j][r];
            }
        }
}

// ---- K2 (MFMA): out[:, 0:2048] = -(z8 @ W[7-k]  +  d1_k @ gW1[k]^T) -----------
// Grid (x=64 rows, y=16 cols) so same-A col-WGs land on one XCD.
// Double-buffered LDS pipeline: 1 barrier per K-step, loads issued before MFMA.
__global__ __launch_bounds__(256) void k_gemm_lo(
    const float* __restrict__ z, const float* __restrict__ d1,
    const unsigned short* __restrict__ WTb, const unsigned short* __restrict__ gW1b,
    float* __restrict__ out) {
    __shared__ uint4 As4[2][512];   // 2 x (128 rows x 32 k bf16) = 16 KB
    __shared__ uint4 Bs4[2][512];   // 2 x (128 cols x 32 k bf16) = 16 KB

    int t = threadIdx.x;
    int lane = t & 63;
    int w = t >> 6;
    int wr = w >> 1, wc = w & 1;
    int b0 = blockIdx.x * 128;
    int n0 = blockIdx.y * 128;
    int k  = n0 >> 8;            // block index 0..7
    int jb = n0 & 255;           // 0 or 128

    const float* Amain = z + (size_t)b0 * ZDIM + 2048;
    const float* Aext  = d1 + ((size_t)k * BATCH + b0) * 32;
    const unsigned short* Bmain = WTb + (size_t)(7 - k) * 65536 + (size_t)jb * 256;
    const unsigned short* Bext  = gW1b + ((size_t)k * 256 + jb) * 32;

    int mq = t >> 2;
    int q  = t & 3;
    int ci0 = (mq & 15) + 16 * q + 64 * (mq >> 4);   // pp=0; pp=1 -> +256

    auto loadAB = [&](int c, float4 (&fa)[2][2], uint4 (&bu)[2]) {
        #pragma unroll
        for (int pp = 0; pp < 2; ++pp) {
            int m = mq + 64 * pp;
            const float* as = (c < 8) ? (Amain + (size_t)m * ZDIM + c * 32 + q * 8)
                                      : (Aext + (size_t)m * 32 + q * 8);
            fa[pp][0] = *(const float4*)(as);
            fa[pp][1] = *(const float4*)(as + 4);
            const unsigned short* bs = (c < 8) ? (Bmain + (size_t)m * 256 + c * 32 + q * 8)
                                               : (Bext + (size_t)m * 32 + q * 8);
            bu[pp] = *(const uint4*)(bs);
        }
    };
    auto storeAB = [&](int buf, float4 (&fa)[2][2], uint4 (&bu)[2]) {
        #pragma unroll
        for (int pp = 0; pp < 2; ++pp) {
            int idx = ci0 + 256 * pp;
            As4[buf][idx] = pack8(fa[pp][0], fa[pp][1]);
            Bs4[buf][idx] = bu[pp];
        }
    };

    f32x4 acc[4][4];
    #pragma unroll
    for (int i = 0; i < 4; ++i)
        #pragma unroll
        for (int j = 0; j < 4; ++j) acc[i][j] = (f32x4){0.f, 0.f, 0.f, 0.f};

    {
        float4 fa[2][2]; uint4 bu[2];
        loadAB(0, fa, bu);
        storeAB(0, fa, bu);
    }
    int cur = 0;
    for (int c = 0; c < 9; ++c) {
        __syncthreads();
        float4 fan[2][2]; uint4 bun[2];
        if (c < 8) loadAB(c + 1, fan, bun);
        bf16x8 af[4], bf[4];
        #pragma unroll
        for (int i = 0; i < 4; ++i) af[i] = __builtin_bit_cast(bf16x8, As4[cur][lane + (wr * 4 + i) * 64]);
        #pragma unroll
        for (int j = 0; j < 4; ++j) bf[j] = __builtin_bit_cast(bf16x8, Bs4[cur][lane + (wc * 4 + j) * 64]);
        #pragma unroll
        for (int i = 0; i < 4; ++i)
            #pragma unroll
            for (int j = 0; j < 4; ++j)
                acc[i][j] = __builtin_amdgcn_mfma_f32_16x16x32_bf16(af[i], bf[j], acc[i][j], 0, 0, 0);
        if (c < 8) storeAB(cur ^ 1, fan, bun);
        cur ^= 1;
    }

    int rquad = lane >> 4;
    int cidx  = lane & 15;
    #pragma unroll
    for (int i = 0; i < 4; ++i) {
        #pragma unroll
        for (int j = 0; j < 4; ++j) {
            float* o = out + (size_t)(b0 + wr * 64 + i * 16 + rquad * 4) * ZDIM
                     + (k * 256 + jb + wc * 64 + j * 16 + cidx);
            #pragma unroll
            for (int r = 0; r < 4; ++r)
                o[(size_t)r * ZDIM] = -acc[i][j][r];
        }
    }
}

// ---- K3 (MFMA): out[:, 2048:] = -(sum_m z_m @ W[7-m]^T + d1_8 @ gW1[8]^T) -----
// 64x64 tiles, K-step 64 (33 iters, zero-padded tail), double-buffered LDS,
// 1 barrier per K-step. Grid (x=128 rows, y=4 cols) -> same-A col-WGs on one XCD.
__global__ __launch_bounds__(256) void k_gemm_hi(
    const float* __restrict__ z, const float* __restrict__ d1,
    const unsigned short* __restrict__ Wb, const unsigned short* __restrict__ gW1b,
    float* __restrict__ out) {
    __shared__ uint4 As4[2][512];   // 2 x (64 rows x 64 k bf16) = 16 KB
    __shared__ uint4 Bs4[2][512];   // 2 x (64 cols x 64 k bf16) = 16 KB

    int t = threadIdx.x;
    int lane = t & 63;
    int w = t >> 6;
    int wr = w & 1, wc = w >> 1;
    int b0 = blockIdx.x * 64;    // batch rows
    int i0 = blockIdx.y * 64;    // hi output col block

    const float* Amain = z + (size_t)b0 * ZDIM;
    const float* Aext  = d1 + ((size_t)8 * BATCH + b0) * 32;
    const unsigned short* Bext = gW1b + (size_t)(8 * 256 + i0) * 32;

    int m = t >> 2;              // 0..63: A row / B col handled by this thread
    int q = t & 3;               // k-subchunk (8 elems) within a 32-chunk
    int ci = (m & 15) + 16 * q + 64 * (m >> 4);   // 0..255; half h -> +256*h

    auto loadAB = [&](int c, float4 (&fa)[2][2], uint4 (&bu)[2]) {
        if (c < 32) {
            int kb = c * 64;
            #pragma unroll
            for (int h = 0; h < 2; ++h) {
                const float* as = Amain + (size_t)m * ZDIM + kb + h * 32 + q * 8;
                fa[h][0] = *(const float4*)(as);
                fa[h][1] = *(const float4*)(as + 4);
            }
            int lag = kb >> 8;
            int j0  = kb & 255;
            const unsigned short* bs = Wb + (size_t)(7 - lag) * 65536
                                         + (size_t)(i0 + m) * 256 + j0 + q * 8;
            bu[0] = *(const uint4*)(bs);
            bu[1] = *(const uint4*)(bs + 32);
        } else {   // tail: d1_8 (32 valid k) + zero pad
            const float* as = Aext + (size_t)m * 32 + q * 8;
            fa[0][0] = *(const float4*)(as);
            fa[0][1] = *(const float4*)(as + 4);
            fa[1][0] = make_float4(0.f, 0.f, 0.f, 0.f);
            fa[1][1] = make_float4(0.f, 0.f, 0.f, 0.f);
            bu[0] = *(const uint4*)(Bext + (size_t)m * 32 + q * 8);
            bu[1] = make_uint4(0u, 0u, 0u, 0u);
        }
    };
    auto storeAB = [&](int buf, float4 (&fa)[2][2], uint4 (&bu)[2]) {
        #pragma unroll
        for (int h = 0; h < 2; ++h) {
            As4[buf][h * 256 + ci] = pack8(fa[h][0], fa[h][1]);
            Bs4[buf][h * 256 + ci] = bu[h];
        }
    };

    f32x4 acc[2][2];
    #pragma unroll
    for (int i = 0; i < 2; ++i)
        #pragma unroll
        for (int j = 0; j < 2; ++j) acc[i][j] = (f32x4){0.f, 0.f, 0.f, 0.f};

    {
        float4 fa[2][2]; uint4 bu[2];
        loadAB(0, fa, bu);
        storeAB(0, fa, bu);
    }
    int cur = 0;
    for (int c = 0; c < 33; ++c) {
        __syncthreads();
        float4 fan[2][2]; uint4 bun[2];
        if (c < 32) loadAB(c + 1, fan, bun);
        #pragma unroll
        for (int h = 0; h < 2; ++h) {
            bf16x8 af[2], bf[2];
            #pragma unroll
            for (int i = 0; i < 2; ++i)
                af[i] = __builtin_bit_cast(bf16x8, As4[cur][h * 256 + lane + (wr * 2 + i) * 64]);
            #pragma unroll
            for (int j = 0; j < 2; ++j)
                bf[j] = __builtin_bit_cast(bf16x8, Bs4[cur][h * 256 + lane + (wc * 2 + j) * 64]);
            #pragma unroll
            for (int i = 0; i < 2; ++i)
                #pragma unroll
                for (int j = 0; j < 2; ++j)
                    acc[i][j] = __builtin_amdgcn_mfma_f32_16x16x32_bf16(af[i], bf[j], acc[i][j], 0, 0, 0);
        }
        if (c < 32) storeAB(cur ^ 1, fan, bun);
        cur ^= 1;
    }

    int rquad = lane >> 4;
    int cidx  = lane & 15;
    #pragma unroll
    for (int i = 0; i < 2; ++i) {
        #pragma unroll
        for (int j = 0; j < 2; ++j) {
            float* o = out + (size_t)(b0 + wr * 32 + i * 16 + rquad * 4) * ZDIM
                     + (2048 + i0 + wc * 32 + j * 16 + cidx);
            #pragma unroll
            for (int r = 0; r < 4; ++r)
                o[(size_t)r * ZDIM] = -acc[i][j][r];
        }
    }
}

extern "C" void kernel_launch(void* const* d_in, const int* in_sizes, int n_in,
                              void* d_out, int out_size, void* d_ws, size_t ws_size,
                              hipStream_t stream) {
    const float* z   = (const float*)d_in[0];
    const float* gW1 = (const float*)d_in[1];
    const float* gb1 = (const float*)d_in[2];
    const float* gW2 = (const float*)d_in[3];
    const float* gb2 = (const float*)d_in[4];
    const float* gW3 = (const float*)d_in[5];
    // d_in[6] = gb3: constant, no grad
    const float* W   = (const float*)d_in[7];
    float* out = (float*)d_out;

    float* ws = (float*)d_ws;
    float*          d1ws = ws;                               // 2359296 f32 (9.4 MB)
    unsigned short* Wb   = (unsigned short*)(ws + 2359296);  // 524288 bf16
    unsigned short* WTb  = Wb + 524288;                      // 524288 bf16
    unsigned short* gW1b = WTb + 524288;                     // 73728 bf16
    unsigned short* g1Tb = gW1b + 73728;                     // 73728 bf16 (~11.8 MB total)

    k_pack<<<dim3(8, 8, 9), 256, 0, stream>>>(W, gW1, Wb, WTb, gW1b, g1Tb);
    k_mlp<<<dim3(64, 9), 256, 0, stream>>>(z, g1Tb, gb1, gW2, gb2, gW3, d1ws);
    k_gemm_lo<<<dim3(64, 16), 256, 0, stream>>>(z, d1ws, WTb, gW1b, out);
    k_gemm_hi<<<dim3(128, 4), 256, 0, stream>>>(z, d1ws, Wb, gW1b, out);
}